// Round 1
// baseline (1336.104 us; speedup 1.0000x reference)
//
#include <hip/hip_runtime.h>
#include <hip/hip_bf16.h>
#include <math.h>

// Problem constants (from reference)
#define B 512
#define D 128
#define K 4096
#define ND 1200000
#define NBANK (ND * (size_t)D)      // 153,600,000
#define INV_TEMP (1.0f / 0.07f)
#define EPS 1e-12f

// ---------- helpers ----------
__device__ inline void blockReduce128_2(float& a, float& b_, float* sh) {
    // 128-thread (2-wave) block reduction of two values; all threads get result
    #pragma unroll
    for (int m = 1; m <= 32; m <<= 1) {
        a  += __shfl_xor(a,  m);
        b_ += __shfl_xor(b_, m);
    }
    int wid = threadIdx.x >> 6;
    if ((threadIdx.x & 63) == 0) { sh[wid * 2] = a; sh[wid * 2 + 1] = b_; }
    __syncthreads();
    a  = sh[0] + sh[2];
    b_ = sh[1] + sh[3];
    __syncthreads();
}

// ---------- K1: normalize s, t; pos logits ----------
__global__ __launch_bounds__(128) void k_norm(
    const float* __restrict__ s_raw, const float* __restrict__ t_raw,
    float* __restrict__ s_n, float* __restrict__ t_n, float* __restrict__ pos)
{
    int b = blockIdx.x, tid = threadIdx.x;
    __shared__ float sh[4];
    float sv = s_raw[b * D + tid];
    float tv = t_raw[b * D + tid];
    float ss = sv * sv, tt = tv * tv;
    blockReduce128_2(ss, tt, sh);
    float sn = sv / fmaxf(sqrtf(ss), EPS);
    float tn = tv / fmaxf(sqrtf(tt), EPS);
    s_n[b * D + tid] = sn;
    t_n[b * D + tid] = tn;
    float d = sn * tn, dummy = 0.0f;
    blockReduce128_2(d, dummy, sh);
    if (tid == 0) pos[b] = d * INV_TEMP;
}

// ---------- K2: gather negatives, dot, online logsumexp per row ----------
__global__ __launch_bounds__(256) void k_neg(
    const float* __restrict__ bank, const float* __restrict__ s_n,
    const float* __restrict__ pos, const int* __restrict__ idxs,
    const int* __restrict__ r, float* __restrict__ loss_part)
{
    int b = blockIdx.x;
    int tid = threadIdx.x;
    __shared__ float4 s_sh[32];
    __shared__ float gmaxs[8], gsums[8];
    if (tid < 32) s_sh[tid] = ((const float4*)(s_n + (size_t)b * D))[tid];
    __syncthreads();

    int group = tid >> 5, lane = tid & 31;
    int self = idxs[b];
    const int* rb = r + (size_t)b * K;
    float4 sv = s_sh[lane];

    float gmax = -1e30f, gsum = 0.0f;
    int kbeg = group * (K / 8), kend = kbeg + (K / 8);
    for (int k0 = kbeg; k0 < kend; k0 += 2) {
        int rv0 = rb[k0], rv1 = rb[k0 + 1];
        int n0 = rv0 + (rv0 >= self ? 1 : 0);
        int n1 = rv1 + (rv1 >= self ? 1 : 0);
        float4 m0 = ((const float4*)bank)[(size_t)n0 * 32 + lane];
        float4 m1 = ((const float4*)bank)[(size_t)n1 * 32 + lane];
        float d0 = m0.x * sv.x + m0.y * sv.y + m0.z * sv.z + m0.w * sv.w;
        float q0 = m0.x * m0.x + m0.y * m0.y + m0.z * m0.z + m0.w * m0.w;
        float d1 = m1.x * sv.x + m1.y * sv.y + m1.z * sv.z + m1.w * sv.w;
        float q1 = m1.x * m1.x + m1.y * m1.y + m1.z * m1.z + m1.w * m1.w;
        // 32-lane butterfly reduce (masks 1..16 stay within each half of the wave)
        #pragma unroll
        for (int m = 1; m <= 16; m <<= 1) {
            d0 += __shfl_xor(d0, m);
            q0 += __shfl_xor(q0, m);
            d1 += __shfl_xor(d1, m);
            q1 += __shfl_xor(q1, m);
        }
        float l0 = d0 / fmaxf(sqrtf(q0), EPS) * INV_TEMP;
        float l1 = d1 / fmaxf(sqrtf(q1), EPS) * INV_TEMP;
        float mx = fmaxf(l0, l1);
        if (mx > gmax) {
            gsum = gsum * __expf(gmax - mx) + __expf(l0 - mx) + __expf(l1 - mx);
            gmax = mx;
        } else {
            gsum += __expf(l0 - gmax) + __expf(l1 - gmax);
        }
    }
    if (lane == 0) { gmaxs[group] = gmax; gsums[group] = gsum; }
    __syncthreads();
    if (tid == 0) {
        float p = pos[b];
        float M = p;
        #pragma unroll
        for (int g = 0; g < 8; ++g) M = fmaxf(M, gmaxs[g]);
        float S = __expf(p - M);
        #pragma unroll
        for (int g = 0; g < 8; ++g) S += gsums[g] * __expf(gmaxs[g] - M);
        loss_part[b] = (M + logf(S)) - p;   // lse - pos_logit
    }
}

// ---------- K2b: final loss reduction ----------
__global__ __launch_bounds__(512) void k_loss(
    const float* __restrict__ lp, float* __restrict__ out)
{
    __shared__ float sh[8];
    float v = lp[threadIdx.x];
    #pragma unroll
    for (int m = 1; m <= 32; m <<= 1) v += __shfl_xor(v, m);
    int wid = threadIdx.x >> 6;
    if ((threadIdx.x & 63) == 0) sh[wid] = v;
    __syncthreads();
    if (threadIdx.x == 0) {
        float s = 0.0f;
        #pragma unroll
        for (int i = 0; i < 8; ++i) s += sh[i];
        out[0] = s * (1.0f / (float)B);
    }
}

// ---------- K3: bulk copy bank -> out+1 ----------
__global__ __launch_bounds__(256) void k_copy(
    const float* __restrict__ bank, float* __restrict__ out)
{
    size_t T = (size_t)gridDim.x * blockDim.x;
    size_t i = (size_t)blockIdx.x * blockDim.x + threadIdx.x;
    // grid sized so 4*T == NBANK exactly
    #pragma unroll
    for (int j = 0; j < 4; ++j) {
        size_t idx = i + (size_t)j * T;
        out[1 + idx] = bank[idx];
    }
}

// ---------- K4: EMA-update scatter (last occurrence wins) ----------
__global__ __launch_bounds__(128) void k_update(
    const float* __restrict__ bank, const float* __restrict__ t_n,
    const int* __restrict__ idxs, float* __restrict__ out)
{
    int b = blockIdx.x, tid = threadIdx.x;
    int idx = idxs[b];
    for (int b2 = b + 1; b2 < B; ++b2)
        if (idxs[b2] == idx) return;   // a later duplicate wins
    float u = 0.5f * bank[(size_t)idx * D + tid] + 0.5f * t_n[(size_t)b * D + tid];
    __shared__ float sh[4];
    float ss = u * u, dummy = 0.0f;
    blockReduce128_2(ss, dummy, sh);
    float un = u / fmaxf(sqrtf(ss), EPS);
    out[1 + (size_t)idx * D + tid] = un;
}

extern "C" void kernel_launch(void* const* d_in, const int* in_sizes, int n_in,
                              void* d_out, int out_size, void* d_ws, size_t ws_size,
                              hipStream_t stream) {
    const float* s_raw = (const float*)d_in[0];
    const float* t_raw = (const float*)d_in[1];
    const float* bank  = (const float*)d_in[2];
    const int*   idxs  = (const int*)d_in[3];
    const int*   r     = (const int*)d_in[4];
    float* out = (float*)d_out;

    // workspace layout (floats)
    float* s_n       = (float*)d_ws;            // B*D
    float* t_n       = s_n + B * D;             // B*D
    float* pos       = t_n + B * D;             // B
    float* loss_part = pos + B;                 // B

    k_norm<<<B, 128, 0, stream>>>(s_raw, t_raw, s_n, t_n, pos);
    k_neg<<<B, 256, 0, stream>>>(bank, s_n, pos, idxs, r, loss_part);
    k_loss<<<1, 512, 0, stream>>>(loss_part, out);
    // NBANK = 153,600,000 = 150000 * 256 * 4 exactly
    k_copy<<<150000, 256, 0, stream>>>(bank, out);
    k_update<<<B, 128, 0, stream>>>(bank, t_n, idxs, out);
}